// Round 11
// baseline (746.239 us; speedup 1.0000x reference)
//
#include <hip/hip_runtime.h>
#include <hip/hip_fp16.h>
#include <math.h>

#define NN 50000
#define EE 800000
#define ETOT (EE + NN)
#define HC 256
#define HEADS 4
#define OUTD 32
#define NB1 196   // ceil(NN/256)

typedef _Float16 f16x8 __attribute__((ext_vector_type(8)));
typedef float f32x4 __attribute__((ext_vector_type(4)));

// ---------------- utility ----------------
__device__ __forceinline__ float wred_sum(float v) {
#pragma unroll
  for (int off = 32; off; off >>= 1) v += __shfl_xor(v, off);
  return v;
}
__device__ __forceinline__ int wred_sum_i(int v) {
#pragma unroll
  for (int off = 32; off; off >>= 1) v += __shfl_xor(v, off);
  return v;
}
__device__ __forceinline__ float qred16(float v) {
#pragma unroll
  for (int off = 1; off < 16; off <<= 1) v += __shfl_xor(v, off);
  return v;
}
__device__ __forceinline__ float lrelu(float x) { return x >= 0.f ? x : 0.2f * x; }

// ---------------- CSR build ----------------
__global__ void hist_k(const int* __restrict__ ei, int* __restrict__ cnt) {
  int e = blockIdx.x * blockDim.x + threadIdx.x;
  if (e >= ETOT) return;
  int d = (e < EE) ? ei[EE + e] : (e - EE);
  atomicAdd(&cnt[d], 1);
}

__global__ void scan1_k(const int* __restrict__ cnt, int* __restrict__ part,
                        int* __restrict__ bsum) {
  __shared__ int s[256];
  int t = threadIdx.x, i = blockIdx.x * 256 + t;
  int v = (i < NN) ? cnt[i] : 0;
  s[t] = v;
  __syncthreads();
#pragma unroll
  for (int off = 1; off < 256; off <<= 1) {
    int u = (t >= off) ? s[t - off] : 0;
    __syncthreads();
    s[t] += u;
    __syncthreads();
  }
  if (i < NN) part[i] = s[t] - v;
  if (t == 255) bsum[blockIdx.x] = s[255];
}

// merged scan2+scan3: each block computes its own prefix of bsum by reduction
__global__ void scan23_k(const int* __restrict__ part, const int* __restrict__ bsum,
                         int* __restrict__ offs, int* __restrict__ cursor) {
  __shared__ int ws[4];
  int t = threadIdx.x, bid = blockIdx.x;
  int wv = t >> 6;
  int v = (t < bid && t < NB1) ? bsum[t] : 0;
  v = wred_sum_i(v);
  if ((t & 63) == 0) ws[wv] = v;
  __syncthreads();
  int bpre = ws[0] + ws[1] + ws[2] + ws[3];
  int i = bid * 256 + t;
  if (i < NN) {
    int o = part[i] + bpre;
    offs[i] = o;
    cursor[i] = o;
  }
  if (i == 0) offs[NN] = ETOT;
}

__global__ void scatter_k(const int* __restrict__ ei, int* __restrict__ cursor,
                          int* __restrict__ elist) {
  int e = blockIdx.x * blockDim.x + threadIdx.x;
  if (e >= ETOT) return;
  int s, d;
  if (e < EE) { s = ei[e]; d = ei[EE + e]; } else { s = d = e - EE; }
  int pos = atomicAdd(&cursor[d], 1);
  elist[pos] = s;
}

// ------- W2+W3 -> fp16, fragment-ordered for 16x16x32 MFMA B (one dispatch) -------
__global__ __launch_bounds__(256) void wswz_both_k(const float* __restrict__ W2,
                                                   const float* __restrict__ W3,
                                                   __half* __restrict__ Bh,
                                                   __half* __restrict__ Bh3) {
  int idx = blockIdx.x * 256 + threadIdx.x;
  if (idx < HC * HC) {
    int k = idx >> 8, n = idx & 255;
    int frag = (n >> 4) * 8 + (k >> 5);
    int ln = (n & 15) + (((k >> 3) & 3) << 4);
    Bh[(frag * 64 + ln) * 8 + (k & 7)] = __float2half(W2[idx]);
  } else {
    int j = idx - HC * HC;
    if (j < HC * OUTD) {
      int k = j / OUTD, n = j % OUTD;
      int frag = (n >> 4) * 8 + (k >> 5);
      int ln = (n & 15) + (((k >> 3) & 3) << 4);
      Bh3[(frag * 64 + ln) * 8 + (k & 7)] = __float2half(W3[j]);
    }
  }
}

// ---------------- layer 1: h = x @ W1 (fp16 out), fused e_src/e_dst ----------------
__global__ __launch_bounds__(256) void l1_h_k(
    const float* __restrict__ x, const float* __restrict__ W1,
    const float* __restrict__ asf, const float* __restrict__ adf,
    __half* __restrict__ hb, float* __restrict__ es, float* __restrict__ ed) {
  int t = threadIdx.x, w = t >> 6;
  float wc[7];
#pragma unroll
  for (int k = 0; k < 7; ++k) wc[k] = W1[k * HC + t];
  float av = asf[t], dv = adf[t];
  for (int i = blockIdx.x; i < NN; i += gridDim.x) {
    float acc = 0.f;
#pragma unroll
    for (int k = 0; k < 7; ++k) acc = fmaf(x[i * 7 + k], wc[k], acc);
    hb[(size_t)i * HC + t] = __float2half(acc);
    float a = wred_sum(acc * av);
    float d = wred_sum(acc * dv);
    if ((t & 63) == 0) { es[i * HEADS + w] = a; ed[i * HEADS + w] = d; }
  }
}

// ------- GAT aggregate v8: XCD channel-slicing.
// slice = blockIdx & 7 -> lands on one XCD (round-robin); that XCD's L2 only
// needs h[:, slice*32 .. +32) = 3.2MB < 4MB L2. Wave = 4 edges x 16 lanes x half2.
// Block 0 also zeroes bnsums (BOTH halves) for the next bn_stats dispatch.
__global__ __launch_bounds__(256) void gat_agg256(
    const __half* __restrict__ hb, const float* __restrict__ es,
    const float* __restrict__ ed, const int* __restrict__ offs,
    const int* __restrict__ elist, const float* __restrict__ bias,
    __half* __restrict__ out, float* __restrict__ bnz) {
  int t = threadIdx.x, wv = t >> 6, lane = t & 63;
  if (blockIdx.x == 0) { bnz[t] = 0.f; bnz[t + 256] = 0.f; }
  int slice = blockIdx.x & 7;
  int i = (blockIdx.x >> 3) * 4 + wv;          // NN % 4 == 0, exact cover
  int eo = lane >> 4;                          // edge group 0..3
  int cp = lane & 15;                          // half2 index within slice
  int hd = slice >> 1;                         // head
  const __half2* hb2 = (const __half2*)hb;
  int base = offs[i], end = offs[i + 1];
  float edv = ed[i * HEADS + hd];
  float2 bv = ((const float2*)bias)[slice * 16 + cp];
  float den = 0.f;
  float2 acc = make_float2(0.f, 0.f);
  for (int e = base + eo; e < end; e += 4) {
    int src = elist[e];
    float ex = __expf(lrelu(es[src * HEADS + hd] + edv));
    __half2 hv = hb2[(size_t)src * 128 + slice * 16 + cp];
    den += ex;
    float2 hf = __half22float2(hv);
    acc.x = fmaf(ex, hf.x, acc.x);
    acc.y = fmaf(ex, hf.y, acc.y);
  }
  den += __shfl_xor(den, 16);
  den += __shfl_xor(den, 32);
  acc.x += __shfl_xor(acc.x, 16);
  acc.x += __shfl_xor(acc.x, 32);
  acc.y += __shfl_xor(acc.y, 16);
  acc.y += __shfl_xor(acc.y, 32);
  if (eo == 0) {
    float inv = 1.f / (den + 1e-16f);
    __half2 o = __floats2half2_rn(fmaf(acc.x, inv, bv.x), fmaf(acc.y, inv, bv.y));
    ((__half2*)out)[(size_t)i * 128 + slice * 16 + cp] = o;
  }
}

// ---------------- BatchNorm stats (fp16 input, standalone) ----------------
__global__ __launch_bounds__(256) void bn_stats_k(const __half* __restrict__ X,
                                                  float* __restrict__ sums) {
  int t = threadIdx.x;
  int r0 = blockIdx.x * 64;
  int rend = min(r0 + 64, NN);
  float s = 0.f, q = 0.f;
  for (int r = r0; r < rend; ++r) {
    float v = __half2float(X[(size_t)r * HC + t]);
    s += v;
    q = fmaf(v, v, q);
  }
  atomicAdd(&sums[t], s);
  atomicAdd(&sums[HC + t], q);
}

// ------- MFMA fp16 GEMM: hbuf = relu(affine(A)) @ W2, 128x128 tile -------
// BN affine computed in-kernel from raw sums (bn_final folded in)
__global__ __launch_bounds__(256) void gemm_mfma_k(const __half* __restrict__ A,
                                                   const __half* __restrict__ Bh,
                                                   const float* __restrict__ bnsums,
                                                   const float* __restrict__ g,
                                                   const float* __restrict__ be,
                                                   const float* __restrict__ asf,
                                                   const float* __restrict__ adf,
                                                   __half* __restrict__ Ch,
                                                   float* __restrict__ es,
                                                   float* __restrict__ ed) {
  __shared__ __align__(16) __half As[128 * 40];  // 128 rows, stride 40 (pad 8)
  __shared__ float abL[512];
  int t = threadIdx.x;
  {
    float mu = bnsums[t] * (1.f / NN);
    float var = bnsums[HC + t] * (1.f / NN) - mu * mu;
    float a = g[t] * rsqrtf(var + 1e-5f);
    abL[t] = a;
    abL[HC + t] = fmaf(-mu, a, be[t]);
  }
  int wv = t >> 6, lane = t & 63;
  int wm = wv >> 1, wn = wv & 1;
  int m0 = blockIdx.x * 128;
  int ntb = blockIdx.y * 8 + wn * 4;
  int srow = t >> 1;
  int skq = (t & 1) * 16;
  int grow = m0 + srow;
  bool ldok = grow < NN;
  const __half* abase = A + (size_t)grow * HC + skq;
  const f16x8* Bf = (const f16x8*)Bh;
  __syncthreads();  // abL visible to all waves

  f32x4 acc[4][4];
  f32x4 zf = {0.f, 0.f, 0.f, 0.f};
#pragma unroll
  for (int mt = 0; mt < 4; ++mt)
#pragma unroll
    for (int nt = 0; nt < 4; ++nt) acc[mt][nt] = zf;

  __half2 hp[8];
#pragma unroll
  for (int j = 0; j < 8; ++j) hp[j] = __half2{(__half)0.f, (__half)0.f};
  if (ldok) {
    *(uint4*)&hp[0] = *(const uint4*)(abase);
    *(uint4*)&hp[4] = *(const uint4*)(abase + 8);
  }

  for (int ks = 0; ks < 8; ++ks) {
    int k0 = ks * 32;
    float xv[16];
#pragma unroll
    for (int j = 0; j < 8; ++j) {
      float2 f = __half22float2(hp[j]);
      xv[2 * j] = f.x;
      xv[2 * j + 1] = f.y;
    }
    if (!ldok) {
#pragma unroll
      for (int j = 0; j < 16; ++j) xv[j] = 0.f;
    }
    f16x8 v0, v1;
#pragma unroll
    for (int j = 0; j < 8; ++j) {
      float a_ = abL[k0 + skq + j], b_ = abL[256 + k0 + skq + j];
      v0[j] = (_Float16)fmaxf(fmaf(xv[j], a_, b_), 0.f);
    }
#pragma unroll
    for (int j = 0; j < 8; ++j) {
      float a_ = abL[k0 + skq + 8 + j], b_ = abL[256 + k0 + skq + 8 + j];
      v1[j] = (_Float16)fmaxf(fmaf(xv[8 + j], a_, b_), 0.f);
    }
    __syncthreads();
    *(f16x8*)&As[srow * 40 + skq] = v0;
    *(f16x8*)&As[srow * 40 + skq + 8] = v1;
    __syncthreads();
    if (ks < 7 && ldok) {
      *(uint4*)&hp[0] = *(const uint4*)(abase + k0 + 32);
      *(uint4*)&hp[4] = *(const uint4*)(abase + k0 + 40);
    }
    f16x8 af[4], bf[4];
    int lr = wm * 64 + (lane & 15);
    int kk = (lane >> 4) * 8;
#pragma unroll
    for (int mt = 0; mt < 4; ++mt)
      af[mt] = *(const f16x8*)&As[(lr + mt * 16) * 40 + kk];
#pragma unroll
    for (int nt = 0; nt < 4; ++nt)
      bf[nt] = Bf[(size_t)((ntb + nt) * 8 + ks) * 64 + lane];
#pragma unroll
    for (int mt = 0; mt < 4; ++mt)
#pragma unroll
      for (int nt = 0; nt < 4; ++nt)
        acc[mt][nt] = __builtin_amdgcn_mfma_f32_16x16x32_f16(af[mt], bf[nt], acc[mt][nt], 0, 0, 0);
  }

  int colb = blockIdx.y * 128 + wn * 64 + (lane & 15);
#pragma unroll
  for (int mt = 0; mt < 4; ++mt) {
    int rowb = m0 + wm * 64 + mt * 16 + (lane >> 4) * 4;
#pragma unroll
    for (int nt = 0; nt < 4; ++nt) {
      int col = colb + nt * 16;
#pragma unroll
      for (int r = 0; r < 4; ++r) {
        int row = rowb + r;
        if (row < NN) Ch[(size_t)row * HC + col] = __float2half(acc[mt][nt][r]);
      }
    }
  }
  float asv[4], adv[4];
#pragma unroll
  for (int nt = 0; nt < 4; ++nt) {
    asv[nt] = asf[colb + nt * 16];
    adv[nt] = adf[colb + nt * 16];
  }
  int head = (blockIdx.y << 1) | wn;
#pragma unroll
  for (int mt = 0; mt < 4; ++mt) {
    int rowb = m0 + wm * 64 + mt * 16 + (lane >> 4) * 4;
#pragma unroll
    for (int r = 0; r < 4; ++r) {
      float pe = 0.f, pd = 0.f;
#pragma unroll
      for (int nt = 0; nt < 4; ++nt) {
        pe = fmaf(acc[mt][nt][r], asv[nt], pe);
        pd = fmaf(acc[mt][nt][r], adv[nt], pd);
      }
      pe = qred16(pe);
      pd = qred16(pd);
      int row = rowb + r;
      if ((lane & 15) == 0 && row < NN) {
        es[row * HEADS + head] = pe;
        ed[row * HEADS + head] = pd;
      }
    }
  }
}

// ------- layer 3 MFMA: h3 = relu(affine(X)) @ W3, fp16 out, fused es3/ed3 -------
__global__ __launch_bounds__(256) void l3_mfma_k(const __half* __restrict__ A,
                                                 const __half* __restrict__ Bh,
                                                 const float* __restrict__ bnsums,
                                                 const float* __restrict__ g,
                                                 const float* __restrict__ be,
                                                 const float* __restrict__ asf,
                                                 const float* __restrict__ adf,
                                                 __half* __restrict__ h3,
                                                 float* __restrict__ es3,
                                                 float* __restrict__ ed3) {
  __shared__ __align__(16) __half As[128 * 40];
  __shared__ float abL[512];
  int t = threadIdx.x;
  {
    float mu = bnsums[t] * (1.f / NN);
    float var = bnsums[HC + t] * (1.f / NN) - mu * mu;
    float a = g[t] * rsqrtf(var + 1e-5f);
    abL[t] = a;
    abL[HC + t] = fmaf(-mu, a, be[t]);
  }
  int wv = t >> 6, lane = t & 63;
  int m0 = blockIdx.x * 128;
  int srow = t >> 1;
  int skq = (t & 1) * 16;
  int grow = m0 + srow;
  bool ldok = grow < NN;
  const __half* abase = A + (size_t)grow * HC + skq;
  const f16x8* Bf = (const f16x8*)Bh;
  __syncthreads();

  f32x4 acc[2][2];
  f32x4 zf = {0.f, 0.f, 0.f, 0.f};
#pragma unroll
  for (int mt = 0; mt < 2; ++mt)
#pragma unroll
    for (int nt = 0; nt < 2; ++nt) acc[mt][nt] = zf;

  __half2 hp[8];
#pragma unroll
  for (int j = 0; j < 8; ++j) hp[j] = __half2{(__half)0.f, (__half)0.f};
  if (ldok) {
    *(uint4*)&hp[0] = *(const uint4*)(abase);
    *(uint4*)&hp[4] = *(const uint4*)(abase + 8);
  }

  for (int ks = 0; ks < 8; ++ks) {
    int k0 = ks * 32;
    float xv[16];
#pragma unroll
    for (int j = 0; j < 8; ++j) {
      float2 f = __half22float2(hp[j]);
      xv[2 * j] = f.x;
      xv[2 * j + 1] = f.y;
    }
    if (!ldok) {
#pragma unroll
      for (int j = 0; j < 16; ++j) xv[j] = 0.f;
    }
    f16x8 v0, v1;
#pragma unroll
    for (int j = 0; j < 8; ++j) {
      float a_ = abL[k0 + skq + j], b_ = abL[256 + k0 + skq + j];
      v0[j] = (_Float16)fmaxf(fmaf(xv[j], a_, b_), 0.f);
    }
#pragma unroll
    for (int j = 0; j < 8; ++j) {
      float a_ = abL[k0 + skq + 8 + j], b_ = abL[256 + k0 + skq + 8 + j];
      v1[j] = (_Float16)fmaxf(fmaf(xv[8 + j], a_, b_), 0.f);
    }
    __syncthreads();
    *(f16x8*)&As[srow * 40 + skq] = v0;
    *(f16x8*)&As[srow * 40 + skq + 8] = v1;
    __syncthreads();
    if (ks < 7 && ldok) {
      *(uint4*)&hp[0] = *(const uint4*)(abase + k0 + 32);
      *(uint4*)&hp[4] = *(const uint4*)(abase + k0 + 40);
    }
    f16x8 af[2], bf[2];
    int lr = wv * 32 + (lane & 15);
    int kk = (lane >> 4) * 8;
#pragma unroll
    for (int mt = 0; mt < 2; ++mt)
      af[mt] = *(const f16x8*)&As[(lr + mt * 16) * 40 + kk];
#pragma unroll
    for (int nt = 0; nt < 2; ++nt)
      bf[nt] = Bf[(size_t)(nt * 8 + ks) * 64 + lane];
#pragma unroll
    for (int mt = 0; mt < 2; ++mt)
#pragma unroll
      for (int nt = 0; nt < 2; ++nt)
        acc[mt][nt] = __builtin_amdgcn_mfma_f32_16x16x32_f16(af[mt], bf[nt], acc[mt][nt], 0, 0, 0);
  }

  float as3v[2], ad3v[2];
#pragma unroll
  for (int nt = 0; nt < 2; ++nt) {
    as3v[nt] = asf[nt * 16 + (lane & 15)];
    ad3v[nt] = adf[nt * 16 + (lane & 15)];
  }
#pragma unroll
  for (int mt = 0; mt < 2; ++mt) {
    int rowb = m0 + wv * 32 + mt * 16 + (lane >> 4) * 4;
#pragma unroll
    for (int r = 0; r < 4; ++r) {
      int row = rowb + r;
      float pe = 0.f, pd = 0.f;
#pragma unroll
      for (int nt = 0; nt < 2; ++nt) {
        int col = nt * 16 + (lane & 15);
        if (row < NN) h3[(size_t)row * OUTD + col] = __float2half(acc[mt][nt][r]);
        pe = fmaf(acc[mt][nt][r], as3v[nt], pe);
        pd = fmaf(acc[mt][nt][r], ad3v[nt], pd);
      }
      pe = qred16(pe);
      pd = qred16(pd);
      if ((lane & 15) == 0 && row < NN) {
        es3[row] = pe;
        ed3[row] = pd;
      }
    }
  }
}

// ------- GAT aggregate, heads=1, ch=32, fp16 h3: 4 edge-groups x 16 lanes -------
__global__ __launch_bounds__(256) void gat_agg32(
    const __half* __restrict__ h3, const float* __restrict__ es3,
    const float* __restrict__ ed3, const int* __restrict__ offs,
    const int* __restrict__ elist, const float* __restrict__ b3,
    float* __restrict__ emb) {
  int t = threadIdx.x, wv = t >> 6, lane = t & 63;
  int g = lane >> 4, cl = lane & 15;
  const __half2* hb2 = (const __half2*)h3;
  int i = blockIdx.x * 4 + wv;
  if (i >= NN) return;
  int base = offs[i], end = offs[i + 1];
  float edv = ed3[i];
  float denom = 0.f;
  float2 acc = make_float2(0.f, 0.f);
  int e8end = base + ((end - base) & ~7);
  for (int e = base; e < e8end; e += 8) {
    int e0 = e + 2 * g;
    int s0 = elist[e0], s1 = elist[e0 + 1];
    float f0 = es3[s0], f1 = es3[s1];
    __half2 r0 = hb2[(size_t)s0 * 16 + cl];
    __half2 r1 = hb2[(size_t)s1 * 16 + cl];
    float x0 = __expf(lrelu(f0 + edv));
    float x1 = __expf(lrelu(f1 + edv));
    denom += x0 + x1;
    float2 h0 = __half22float2(r0), h1 = __half22float2(r1);
    acc.x = fmaf(x0, h0.x, fmaf(x1, h1.x, acc.x));
    acc.y = fmaf(x0, h0.y, fmaf(x1, h1.y, acc.y));
  }
  for (int e = e8end + g; e < end; e += 4) {
    int s0 = elist[e];
    float x0 = __expf(lrelu(es3[s0] + edv));
    __half2 r0 = hb2[(size_t)s0 * 16 + cl];
    denom += x0;
    float2 h0 = __half22float2(r0);
    acc.x = fmaf(x0, h0.x, acc.x);
    acc.y = fmaf(x0, h0.y, acc.y);
  }
#pragma unroll
  for (int off = 16; off < 64; off <<= 1) {
    denom += __shfl_xor(denom, off);
    acc.x += __shfl_xor(acc.x, off);
    acc.y += __shfl_xor(acc.y, off);
  }
  if (g == 0) {
    float inv = 1.f / (denom + 1e-16f);
    float2 o;
    o.x = fmaf(acc.x, inv, b3[2 * cl]);
    o.y = fmaf(acc.y, inv, b3[2 * cl + 1]);
    ((float2*)(emb + (size_t)i * OUTD))[cl] = o;
  }
}

// ---------------- MLP head (c1 computed per-block) ----------------
__global__ __launch_bounds__(256) void mlp_k(
    const float* __restrict__ emb, const int* __restrict__ srcn,
    const float* __restrict__ Wm1, const float* __restrict__ bm1,
    const float* __restrict__ Wm2, const float* __restrict__ bm2,
    const float* __restrict__ Wm3, const float* __restrict__ bm3,
    float* __restrict__ outp) {
  __shared__ float WL1s[32][64];
  __shared__ float WL2s[64][32];
  __shared__ float W3s[32];
  __shared__ float c1s[64];
  __shared__ float zsrc[32];
  int t = threadIdx.x;
  int sn = srcn[0];
  if (t < 32) zsrc[t] = emb[(size_t)sn * OUTD + t];
  for (int q = t; q < 2048; q += 256) WL1s[q >> 6][q & 63] = Wm1[(32 + (q >> 6)) * 64 + (q & 63)];
  for (int q = t; q < 2048; q += 256) WL2s[q >> 5][q & 31] = Wm2[q];
  if (t < 32) W3s[t] = Wm3[t];
  __syncthreads();
  if (t < 64) {
    float a = bm1[t];
#pragma unroll 8
    for (int k = 0; k < 32; ++k) a = fmaf(zsrc[k], Wm1[k * 64 + t], a);
    c1s[t] = a;
  }
  __syncthreads();
  int wv = t >> 6, lane = t & 63;
  int p = lane >> 5, c = lane & 31;
  float bm2v = bm2[c];
  float bm3v = bm3[0];
  for (int node = blockIdx.x * 4 + wv; node < NN; node += gridDim.x * 4) {
    float zv = (lane < 32) ? emb[(size_t)node * OUTD + lane] : 0.f;
    float a1 = c1s[lane];
#pragma unroll
    for (int k = 0; k < 32; ++k) a1 = fmaf(__shfl(zv, k), WL1s[k][lane], a1);
    float u1 = fmaxf(a1, 0.f);
    float a2 = 0.f;
#pragma unroll
    for (int j = 0; j < 32; ++j) a2 = fmaf(__shfl(u1, p * 32 + j), WL2s[p * 32 + j][c], a2);
    a2 += __shfl_xor(a2, 32);
    float v = 0.f;
    if (lane < 32) {
      float u2 = fmaxf(a2 + bm2v, 0.f);
      v = u2 * W3s[c];
    }
    v = wred_sum(v);
    if (lane == 0) outp[node] = 1.f / (1.f + __expf(-(v + bm3v)));
  }
}

// ---------------- host launcher ----------------
extern "C" void kernel_launch(void* const* d_in, const int* in_sizes, int n_in,
                              void* d_out, int out_size, void* d_ws, size_t ws_size,
                              hipStream_t stream) {
  const float* x   = (const float*)d_in[0];
  const int* eidx  = (const int*)d_in[1];
  const int* srcn  = (const int*)d_in[2];
  const float* W1  = (const float*)d_in[3];
  const float* as1 = (const float*)d_in[4];
  const float* ad1 = (const float*)d_in[5];
  const float* b1  = (const float*)d_in[6];
  const float* g1  = (const float*)d_in[7];
  const float* be1 = (const float*)d_in[8];
  const float* W2  = (const float*)d_in[9];
  const float* as2 = (const float*)d_in[10];
  const float* ad2 = (const float*)d_in[11];
  const float* b2  = (const float*)d_in[12];
  const float* g2  = (const float*)d_in[13];
  const float* be2 = (const float*)d_in[14];
  const float* W3  = (const float*)d_in[15];
  const float* as3 = (const float*)d_in[16];
  const float* ad3 = (const float*)d_in[17];
  const float* b3  = (const float*)d_in[18];
  const float* Wm1 = (const float*)d_in[19];
  const float* bm1 = (const float*)d_in[20];
  const float* Wm2 = (const float*)d_in[21];
  const float* bm2 = (const float*)d_in[22];
  const float* Wm3 = (const float*)d_in[23];
  const float* bm3 = (const float*)d_in[24];
  float* outp = (float*)d_out;

  // workspace carve (256B-aligned chunks)
  char* wp = (char*)d_ws;
  auto carve = [&](size_t bytes) {
    void* p = (void*)wp;
    wp += (bytes + 255) & ~(size_t)255;
    return p;
  };
  __half* aggB  = (__half*)carve((size_t)NN * HC * 2);   // fp16 agg output
  __half* hbuf  = (__half*)carve((size_t)NN * HC * 2);   // fp16 h
  __half* h3h   = (__half*)carve((size_t)NN * OUTD * 2); // fp16 h3
  float* emb    = (float*)carve((size_t)NN * OUTD * 4);
  float* es     = (float*)carve((size_t)NN * HEADS * 4);
  float* ed     = (float*)carve((size_t)NN * HEADS * 4);
  float* es3    = (float*)carve((size_t)NN * 4);
  float* ed3    = (float*)carve((size_t)NN * 4);
  float* bnsums = (float*)carve(2 * HC * 4);
  __half* Bh    = (__half*)carve((size_t)HC * HC * 2);   // swizzled W2 fp16
  __half* Bh3   = (__half*)carve((size_t)HC * OUTD * 2); // swizzled W3 fp16
  int* offs     = (int*)carve((NN + 4) * 4);
  int* cursor   = (int*)carve(NN * 4);
  int* elist    = (int*)carve((size_t)ETOT * 4);
  int* part     = (int*)carve(NN * 4);
  int* bsum     = (int*)carve(256 * 4);

  const int TB = 256;
  const int gE = (ETOT + TB - 1) / TB;
  const int gN4 = (NN + 3) / 4;            // 12500
  const int gAgg = 8 * gN4;                // 100000 slice-blocks

  // ---- CSR build ----
  hipMemsetAsync(cursor, 0, (size_t)NN * 4, stream);
  hist_k<<<gE, TB, 0, stream>>>(eidx, cursor);
  scan1_k<<<NB1, TB, 0, stream>>>(cursor, part, bsum);
  scan23_k<<<NB1, TB, 0, stream>>>(part, bsum, offs, cursor);
  scatter_k<<<gE, TB, 0, stream>>>(eidx, cursor, elist);
  wswz_both_k<<<(HC * HC + HC * OUTD + TB - 1) / TB, TB, 0, stream>>>(W2, W3, Bh, Bh3);

  // ---- layer 1 ----
  l1_h_k<<<2048, TB, 0, stream>>>(x, W1, as1, ad1, hbuf, es, ed);
  gat_agg256<<<gAgg, TB, 0, stream>>>(hbuf, es, ed, offs, elist, b1, aggB, bnsums);
  bn_stats_k<<<(NN + 63) / 64, TB, 0, stream>>>(aggB, bnsums);

  // ---- layer 2: MFMA GEMM (BN1 affine computed in-kernel; es2/ed2 fused) ----
  gemm_mfma_k<<<dim3((NN + 127) / 128, HC / 128), TB, 0, stream>>>(
      aggB, Bh, bnsums, g1, be1, as2, ad2, hbuf, es, ed);
  gat_agg256<<<gAgg, TB, 0, stream>>>(hbuf, es, ed, offs, elist, b2, aggB, bnsums);
  bn_stats_k<<<(NN + 63) / 64, TB, 0, stream>>>(aggB, bnsums);

  // ---- layer 3: MFMA (BN2 affine computed in-kernel; es3/ed3 fused) ----
  l3_mfma_k<<<(NN + 127) / 128, TB, 0, stream>>>(
      aggB, Bh3, bnsums, g2, be2, as3, ad3, h3h, es3, ed3);
  gat_agg32<<<gN4, TB, 0, stream>>>(h3h, es3, ed3, offs, elist, b3, emb);

  // ---- MLP head ----
  mlp_k<<<512, TB, 0, stream>>>(emb, srcn, Wm1, bm1, Wm2, bm2, Wm3, bm3, outp);
}

// Round 12
// 446.541 us; speedup vs baseline: 1.6712x; 1.6712x over previous
//
#include <hip/hip_runtime.h>
#include <hip/hip_fp16.h>
#include <math.h>

#define NN 50000
#define EE 800000
#define ETOT (EE + NN)
#define HC 256
#define HEADS 4
#define OUTD 32
#define NB1 196   // ceil(NN/256)

typedef _Float16 f16x8 __attribute__((ext_vector_type(8)));
typedef float f32x4 __attribute__((ext_vector_type(4)));

// ---------------- utility ----------------
__device__ __forceinline__ float wred_sum(float v) {
#pragma unroll
  for (int off = 32; off; off >>= 1) v += __shfl_xor(v, off);
  return v;
}
__device__ __forceinline__ int wred_sum_i(int v) {
#pragma unroll
  for (int off = 32; off; off >>= 1) v += __shfl_xor(v, off);
  return v;
}
__device__ __forceinline__ float qred16(float v) {
#pragma unroll
  for (int off = 1; off < 16; off <<= 1) v += __shfl_xor(v, off);
  return v;
}
__device__ __forceinline__ float lrelu(float x) { return x >= 0.f ? x : 0.2f * x; }

// ---------------- CSR build ----------------
__global__ void hist_k(const int* __restrict__ ei, int* __restrict__ cnt) {
  int e = blockIdx.x * blockDim.x + threadIdx.x;
  if (e >= ETOT) return;
  int d = (e < EE) ? ei[EE + e] : (e - EE);
  atomicAdd(&cnt[d], 1);
}

__global__ void scan1_k(const int* __restrict__ cnt, int* __restrict__ part,
                        int* __restrict__ bsum) {
  __shared__ int s[256];
  int t = threadIdx.x, i = blockIdx.x * 256 + t;
  int v = (i < NN) ? cnt[i] : 0;
  s[t] = v;
  __syncthreads();
#pragma unroll
  for (int off = 1; off < 256; off <<= 1) {
    int u = (t >= off) ? s[t - off] : 0;
    __syncthreads();
    s[t] += u;
    __syncthreads();
  }
  if (i < NN) part[i] = s[t] - v;
  if (t == 255) bsum[blockIdx.x] = s[255];
}

// merged scan2+scan3: each block computes its own prefix of bsum by reduction
__global__ void scan23_k(const int* __restrict__ part, const int* __restrict__ bsum,
                         int* __restrict__ offs, int* __restrict__ cursor) {
  __shared__ int ws[4];
  int t = threadIdx.x, bid = blockIdx.x;
  int wv = t >> 6;
  int v = (t < bid && t < NB1) ? bsum[t] : 0;
  v = wred_sum_i(v);
  if ((t & 63) == 0) ws[wv] = v;
  __syncthreads();
  int bpre = ws[0] + ws[1] + ws[2] + ws[3];
  int i = bid * 256 + t;
  if (i < NN) {
    int o = part[i] + bpre;
    offs[i] = o;
    cursor[i] = o;
  }
  if (i == 0) offs[NN] = ETOT;
}

__global__ void scatter_k(const int* __restrict__ ei, int* __restrict__ cursor,
                          int* __restrict__ elist) {
  int e = blockIdx.x * blockDim.x + threadIdx.x;
  if (e >= ETOT) return;
  int s, d;
  if (e < EE) { s = ei[e]; d = ei[EE + e]; } else { s = d = e - EE; }
  int pos = atomicAdd(&cursor[d], 1);
  elist[pos] = s;
}

// ------- W2+W3 -> fp16, fragment-ordered for 16x16x32 MFMA B (one dispatch) -------
__global__ __launch_bounds__(256) void wswz_both_k(const float* __restrict__ W2,
                                                   const float* __restrict__ W3,
                                                   __half* __restrict__ Bh,
                                                   __half* __restrict__ Bh3) {
  int idx = blockIdx.x * 256 + threadIdx.x;
  if (idx < HC * HC) {
    int k = idx >> 8, n = idx & 255;
    int frag = (n >> 4) * 8 + (k >> 5);
    int ln = (n & 15) + (((k >> 3) & 3) << 4);
    Bh[(frag * 64 + ln) * 8 + (k & 7)] = __float2half(W2[idx]);
  } else {
    int j = idx - HC * HC;
    if (j < HC * OUTD) {
      int k = j / OUTD, n = j % OUTD;
      int frag = (n >> 4) * 8 + (k >> 5);
      int ln = (n & 15) + (((k >> 3) & 3) << 4);
      Bh3[(frag * 64 + ln) * 8 + (k & 7)] = __float2half(W3[j]);
    }
  }
}

// ---------------- layer 1: h = x @ W1 (fp16 out), fused e_src/e_dst ----------------
__global__ __launch_bounds__(256) void l1_h_k(
    const float* __restrict__ x, const float* __restrict__ W1,
    const float* __restrict__ asf, const float* __restrict__ adf,
    __half* __restrict__ hb, float* __restrict__ es, float* __restrict__ ed) {
  int t = threadIdx.x, w = t >> 6;
  float wc[7];
#pragma unroll
  for (int k = 0; k < 7; ++k) wc[k] = W1[k * HC + t];
  float av = asf[t], dv = adf[t];
  for (int i = blockIdx.x; i < NN; i += gridDim.x) {
    float acc = 0.f;
#pragma unroll
    for (int k = 0; k < 7; ++k) acc = fmaf(x[i * 7 + k], wc[k], acc);
    hb[(size_t)i * HC + t] = __float2half(acc);
    float a = wred_sum(acc * av);
    float d = wred_sum(acc * dv);
    if ((t & 63) == 0) { es[i * HEADS + w] = a; ed[i * HEADS + w] = d; }
  }
}

// ------- GAT aggregate (R8 proven form): wave-per-node, 8-edge int4 batches,
//         fp16 in/out. Block 0 zeroes bnsums (BOTH halves) for next bn_stats. -------
__global__ __launch_bounds__(256) void gat_agg256(
    const __half* __restrict__ hb, const float* __restrict__ es,
    const float* __restrict__ ed, const int* __restrict__ offs,
    const int* __restrict__ elist, const float* __restrict__ bias,
    __half* __restrict__ out, float* __restrict__ bnz) {
  int t = threadIdx.x, wv = t >> 6, lane = t & 63;
  if (blockIdx.x == 0) { bnz[t] = 0.f; bnz[t + 256] = 0.f; }
  int hd = lane >> 4;
  float4 bv = ((const float4*)bias)[lane];
  const float2* hb4 = (const float2*)hb;
  int i = blockIdx.x * 4 + wv;
  if (i >= NN) return;
  int base = offs[i], end = offs[i + 1];
  float edv = ed[i * HEADS + hd];
  float denom = 0.f;
  float4 acc = make_float4(0.f, 0.f, 0.f, 0.f);

#define ACC1(X_, R_)                                   \
  {                                                    \
    float2 h01_ = __half22float2(*(__half2*)&R_.x);    \
    float2 h23_ = __half22float2(*(__half2*)&R_.y);    \
    acc.x = fmaf(X_, h01_.x, acc.x);                   \
    acc.y = fmaf(X_, h01_.y, acc.y);                   \
    acc.z = fmaf(X_, h23_.x, acc.z);                   \
    acc.w = fmaf(X_, h23_.y, acc.w);                   \
  }
#define EDGE1(SRC)                                          \
  {                                                         \
    int src_ = (SRC);                                       \
    float ex_ = __expf(lrelu(es[src_ * HEADS + hd] + edv)); \
    denom += ex_;                                           \
    float2 raw_ = hb4[(size_t)src_ * 64 + lane];            \
    ACC1(ex_, raw_);                                        \
  }

  int e = base;
  int alim = (base + 3) & ~3;
  for (; e < end && e < alim; ++e) EDGE1(elist[e]);
  for (; e + 8 <= end; e += 8) {
    int4 ia = *(const int4*)&elist[e];
    int4 ib = *(const int4*)&elist[e + 4];
    float f0 = es[ia.x * HEADS + hd], f1 = es[ia.y * HEADS + hd];
    float f2 = es[ia.z * HEADS + hd], f3 = es[ia.w * HEADS + hd];
    float f4 = es[ib.x * HEADS + hd], f5 = es[ib.y * HEADS + hd];
    float f6 = es[ib.z * HEADS + hd], f7 = es[ib.w * HEADS + hd];
    float2 r0 = hb4[(size_t)ia.x * 64 + lane];
    float2 r1 = hb4[(size_t)ia.y * 64 + lane];
    float2 r2 = hb4[(size_t)ia.z * 64 + lane];
    float2 r3 = hb4[(size_t)ia.w * 64 + lane];
    float2 r4 = hb4[(size_t)ib.x * 64 + lane];
    float2 r5 = hb4[(size_t)ib.y * 64 + lane];
    float2 r6 = hb4[(size_t)ib.z * 64 + lane];
    float2 r7 = hb4[(size_t)ib.w * 64 + lane];
    float x0 = __expf(lrelu(f0 + edv)), x1 = __expf(lrelu(f1 + edv));
    float x2 = __expf(lrelu(f2 + edv)), x3 = __expf(lrelu(f3 + edv));
    float x4 = __expf(lrelu(f4 + edv)), x5 = __expf(lrelu(f5 + edv));
    float x6 = __expf(lrelu(f6 + edv)), x7 = __expf(lrelu(f7 + edv));
    denom += ((x0 + x1) + (x2 + x3)) + ((x4 + x5) + (x6 + x7));
    ACC1(x0, r0); ACC1(x1, r1); ACC1(x2, r2); ACC1(x3, r3);
    ACC1(x4, r4); ACC1(x5, r5); ACC1(x6, r6); ACC1(x7, r7);
  }
  for (; e + 4 <= end; e += 4) {
    int4 ia = *(const int4*)&elist[e];
    float f0 = es[ia.x * HEADS + hd], f1 = es[ia.y * HEADS + hd];
    float f2 = es[ia.z * HEADS + hd], f3 = es[ia.w * HEADS + hd];
    float2 r0 = hb4[(size_t)ia.x * 64 + lane];
    float2 r1 = hb4[(size_t)ia.y * 64 + lane];
    float2 r2 = hb4[(size_t)ia.z * 64 + lane];
    float2 r3 = hb4[(size_t)ia.w * 64 + lane];
    float x0 = __expf(lrelu(f0 + edv)), x1 = __expf(lrelu(f1 + edv));
    float x2 = __expf(lrelu(f2 + edv)), x3 = __expf(lrelu(f3 + edv));
    denom += (x0 + x1) + (x2 + x3);
    ACC1(x0, r0); ACC1(x1, r1); ACC1(x2, r2); ACC1(x3, r3);
  }
  for (; e < end; ++e) EDGE1(elist[e]);
#undef EDGE1
#undef ACC1

  float inv = 1.f / (denom + 1e-16f);
  __half2 o01 = __floats2half2_rn(fmaf(acc.x, inv, bv.x), fmaf(acc.y, inv, bv.y));
  __half2 o23 = __floats2half2_rn(fmaf(acc.z, inv, bv.z), fmaf(acc.w, inv, bv.w));
  uint2 pk;
  pk.x = *(unsigned int*)&o01;
  pk.y = *(unsigned int*)&o23;
  ((uint2*)(out + (size_t)i * HC))[lane] = pk;
}

// ---------------- BatchNorm stats (fp16 input, standalone) ----------------
__global__ __launch_bounds__(256) void bn_stats_k(const __half* __restrict__ X,
                                                  float* __restrict__ sums) {
  int t = threadIdx.x;
  int r0 = blockIdx.x * 64;
  int rend = min(r0 + 64, NN);
  float s = 0.f, q = 0.f;
  for (int r = r0; r < rend; ++r) {
    float v = __half2float(X[(size_t)r * HC + t]);
    s += v;
    q = fmaf(v, v, q);
  }
  atomicAdd(&sums[t], s);
  atomicAdd(&sums[HC + t], q);
}

// ------- MFMA fp16 GEMM: hbuf = relu(affine(A)) @ W2, 128x128 tile -------
// BN affine computed in-kernel from raw sums (bn_final folded in)
__global__ __launch_bounds__(256) void gemm_mfma_k(const __half* __restrict__ A,
                                                   const __half* __restrict__ Bh,
                                                   const float* __restrict__ bnsums,
                                                   const float* __restrict__ g,
                                                   const float* __restrict__ be,
                                                   const float* __restrict__ asf,
                                                   const float* __restrict__ adf,
                                                   __half* __restrict__ Ch,
                                                   float* __restrict__ es,
                                                   float* __restrict__ ed) {
  __shared__ __align__(16) __half As[128 * 40];  // 128 rows, stride 40 (pad 8)
  __shared__ float abL[512];
  int t = threadIdx.x;
  {
    float mu = bnsums[t] * (1.f / NN);
    float var = bnsums[HC + t] * (1.f / NN) - mu * mu;
    float a = g[t] * rsqrtf(var + 1e-5f);
    abL[t] = a;
    abL[HC + t] = fmaf(-mu, a, be[t]);
  }
  int wv = t >> 6, lane = t & 63;
  int wm = wv >> 1, wn = wv & 1;
  int m0 = blockIdx.x * 128;
  int ntb = blockIdx.y * 8 + wn * 4;
  int srow = t >> 1;
  int skq = (t & 1) * 16;
  int grow = m0 + srow;
  bool ldok = grow < NN;
  const __half* abase = A + (size_t)grow * HC + skq;
  const f16x8* Bf = (const f16x8*)Bh;
  __syncthreads();  // abL visible to all waves

  f32x4 acc[4][4];
  f32x4 zf = {0.f, 0.f, 0.f, 0.f};
#pragma unroll
  for (int mt = 0; mt < 4; ++mt)
#pragma unroll
    for (int nt = 0; nt < 4; ++nt) acc[mt][nt] = zf;

  __half2 hp[8];
#pragma unroll
  for (int j = 0; j < 8; ++j) hp[j] = __half2{(__half)0.f, (__half)0.f};
  if (ldok) {
    *(uint4*)&hp[0] = *(const uint4*)(abase);
    *(uint4*)&hp[4] = *(const uint4*)(abase + 8);
  }

  for (int ks = 0; ks < 8; ++ks) {
    int k0 = ks * 32;
    float xv[16];
#pragma unroll
    for (int j = 0; j < 8; ++j) {
      float2 f = __half22float2(hp[j]);
      xv[2 * j] = f.x;
      xv[2 * j + 1] = f.y;
    }
    if (!ldok) {
#pragma unroll
      for (int j = 0; j < 16; ++j) xv[j] = 0.f;
    }
    f16x8 v0, v1;
#pragma unroll
    for (int j = 0; j < 8; ++j) {
      float a_ = abL[k0 + skq + j], b_ = abL[256 + k0 + skq + j];
      v0[j] = (_Float16)fmaxf(fmaf(xv[j], a_, b_), 0.f);
    }
#pragma unroll
    for (int j = 0; j < 8; ++j) {
      float a_ = abL[k0 + skq + 8 + j], b_ = abL[256 + k0 + skq + 8 + j];
      v1[j] = (_Float16)fmaxf(fmaf(xv[8 + j], a_, b_), 0.f);
    }
    __syncthreads();
    *(f16x8*)&As[srow * 40 + skq] = v0;
    *(f16x8*)&As[srow * 40 + skq + 8] = v1;
    __syncthreads();
    if (ks < 7 && ldok) {
      *(uint4*)&hp[0] = *(const uint4*)(abase + k0 + 32);
      *(uint4*)&hp[4] = *(const uint4*)(abase + k0 + 40);
    }
    f16x8 af[4], bf[4];
    int lr = wm * 64 + (lane & 15);
    int kk = (lane >> 4) * 8;
#pragma unroll
    for (int mt = 0; mt < 4; ++mt)
      af[mt] = *(const f16x8*)&As[(lr + mt * 16) * 40 + kk];
#pragma unroll
    for (int nt = 0; nt < 4; ++nt)
      bf[nt] = Bf[(size_t)((ntb + nt) * 8 + ks) * 64 + lane];
#pragma unroll
    for (int mt = 0; mt < 4; ++mt)
#pragma unroll
      for (int nt = 0; nt < 4; ++nt)
        acc[mt][nt] = __builtin_amdgcn_mfma_f32_16x16x32_f16(af[mt], bf[nt], acc[mt][nt], 0, 0, 0);
  }

  int colb = blockIdx.y * 128 + wn * 64 + (lane & 15);
#pragma unroll
  for (int mt = 0; mt < 4; ++mt) {
    int rowb = m0 + wm * 64 + mt * 16 + (lane >> 4) * 4;
#pragma unroll
    for (int nt = 0; nt < 4; ++nt) {
      int col = colb + nt * 16;
#pragma unroll
      for (int r = 0; r < 4; ++r) {
        int row = rowb + r;
        if (row < NN) Ch[(size_t)row * HC + col] = __float2half(acc[mt][nt][r]);
      }
    }
  }
  float asv[4], adv[4];
#pragma unroll
  for (int nt = 0; nt < 4; ++nt) {
    asv[nt] = asf[colb + nt * 16];
    adv[nt] = adf[colb + nt * 16];
  }
  int head = (blockIdx.y << 1) | wn;
#pragma unroll
  for (int mt = 0; mt < 4; ++mt) {
    int rowb = m0 + wm * 64 + mt * 16 + (lane >> 4) * 4;
#pragma unroll
    for (int r = 0; r < 4; ++r) {
      float pe = 0.f, pd = 0.f;
#pragma unroll
      for (int nt = 0; nt < 4; ++nt) {
        pe = fmaf(acc[mt][nt][r], asv[nt], pe);
        pd = fmaf(acc[mt][nt][r], adv[nt], pd);
      }
      pe = qred16(pe);
      pd = qred16(pd);
      int row = rowb + r;
      if ((lane & 15) == 0 && row < NN) {
        es[row * HEADS + head] = pe;
        ed[row * HEADS + head] = pd;
      }
    }
  }
}

// ------- layer 3 MFMA: h3 = relu(affine(X)) @ W3, fp16 out, fused es3/ed3 -------
__global__ __launch_bounds__(256) void l3_mfma_k(const __half* __restrict__ A,
                                                 const __half* __restrict__ Bh,
                                                 const float* __restrict__ bnsums,
                                                 const float* __restrict__ g,
                                                 const float* __restrict__ be,
                                                 const float* __restrict__ asf,
                                                 const float* __restrict__ adf,
                                                 __half* __restrict__ h3,
                                                 float* __restrict__ es3,
                                                 float* __restrict__ ed3) {
  __shared__ __align__(16) __half As[128 * 40];
  __shared__ float abL[512];
  int t = threadIdx.x;
  {
    float mu = bnsums[t] * (1.f / NN);
    float var = bnsums[HC + t] * (1.f / NN) - mu * mu;
    float a = g[t] * rsqrtf(var + 1e-5f);
    abL[t] = a;
    abL[HC + t] = fmaf(-mu, a, be[t]);
  }
  int wv = t >> 6, lane = t & 63;
  int m0 = blockIdx.x * 128;
  int srow = t >> 1;
  int skq = (t & 1) * 16;
  int grow = m0 + srow;
  bool ldok = grow < NN;
  const __half* abase = A + (size_t)grow * HC + skq;
  const f16x8* Bf = (const f16x8*)Bh;
  __syncthreads();

  f32x4 acc[2][2];
  f32x4 zf = {0.f, 0.f, 0.f, 0.f};
#pragma unroll
  for (int mt = 0; mt < 2; ++mt)
#pragma unroll
    for (int nt = 0; nt < 2; ++nt) acc[mt][nt] = zf;

  __half2 hp[8];
#pragma unroll
  for (int j = 0; j < 8; ++j) hp[j] = __half2{(__half)0.f, (__half)0.f};
  if (ldok) {
    *(uint4*)&hp[0] = *(const uint4*)(abase);
    *(uint4*)&hp[4] = *(const uint4*)(abase + 8);
  }

  for (int ks = 0; ks < 8; ++ks) {
    int k0 = ks * 32;
    float xv[16];
#pragma unroll
    for (int j = 0; j < 8; ++j) {
      float2 f = __half22float2(hp[j]);
      xv[2 * j] = f.x;
      xv[2 * j + 1] = f.y;
    }
    if (!ldok) {
#pragma unroll
      for (int j = 0; j < 16; ++j) xv[j] = 0.f;
    }
    f16x8 v0, v1;
#pragma unroll
    for (int j = 0; j < 8; ++j) {
      float a_ = abL[k0 + skq + j], b_ = abL[256 + k0 + skq + j];
      v0[j] = (_Float16)fmaxf(fmaf(xv[j], a_, b_), 0.f);
    }
#pragma unroll
    for (int j = 0; j < 8; ++j) {
      float a_ = abL[k0 + skq + 8 + j], b_ = abL[256 + k0 + skq + 8 + j];
      v1[j] = (_Float16)fmaxf(fmaf(xv[8 + j], a_, b_), 0.f);
    }
    __syncthreads();
    *(f16x8*)&As[srow * 40 + skq] = v0;
    *(f16x8*)&As[srow * 40 + skq + 8] = v1;
    __syncthreads();
    if (ks < 7 && ldok) {
      *(uint4*)&hp[0] = *(const uint4*)(abase + k0 + 32);
      *(uint4*)&hp[4] = *(const uint4*)(abase + k0 + 40);
    }
    f16x8 af[2], bf[2];
    int lr = wv * 32 + (lane & 15);
    int kk = (lane >> 4) * 8;
#pragma unroll
    for (int mt = 0; mt < 2; ++mt)
      af[mt] = *(const f16x8*)&As[(lr + mt * 16) * 40 + kk];
#pragma unroll
    for (int nt = 0; nt < 2; ++nt)
      bf[nt] = Bf[(size_t)(nt * 8 + ks) * 64 + lane];
#pragma unroll
    for (int mt = 0; mt < 2; ++mt)
#pragma unroll
      for (int nt = 0; nt < 2; ++nt)
        acc[mt][nt] = __builtin_amdgcn_mfma_f32_16x16x32_f16(af[mt], bf[nt], acc[mt][nt], 0, 0, 0);
  }

  float as3v[2], ad3v[2];
#pragma unroll
  for (int nt = 0; nt < 2; ++nt) {
    as3v[nt] = asf[nt * 16 + (lane & 15)];
    ad3v[nt] = adf[nt * 16 + (lane & 15)];
  }
#pragma unroll
  for (int mt = 0; mt < 2; ++mt) {
    int rowb = m0 + wv * 32 + mt * 16 + (lane >> 4) * 4;
#pragma unroll
    for (int r = 0; r < 4; ++r) {
      int row = rowb + r;
      float pe = 0.f, pd = 0.f;
#pragma unroll
      for (int nt = 0; nt < 2; ++nt) {
        int col = nt * 16 + (lane & 15);
        if (row < NN) h3[(size_t)row * OUTD + col] = __float2half(acc[mt][nt][r]);
        pe = fmaf(acc[mt][nt][r], as3v[nt], pe);
        pd = fmaf(acc[mt][nt][r], ad3v[nt], pd);
      }
      pe = qred16(pe);
      pd = qred16(pd);
      if ((lane & 15) == 0 && row < NN) {
        es3[row] = pe;
        ed3[row] = pd;
      }
    }
  }
}

// ------- GAT aggregate, heads=1, ch=32, fp16 h3: 4 edge-groups x 16 lanes -------
__global__ __launch_bounds__(256) void gat_agg32(
    const __half* __restrict__ h3, const float* __restrict__ es3,
    const float* __restrict__ ed3, const int* __restrict__ offs,
    const int* __restrict__ elist, const float* __restrict__ b3,
    float* __restrict__ emb) {
  int t = threadIdx.x, wv = t >> 6, lane = t & 63;
  int g = lane >> 4, cl = lane & 15;
  const __half2* hb2 = (const __half2*)h3;
  int i = blockIdx.x * 4 + wv;
  if (i >= NN) return;
  int base = offs[i], end = offs[i + 1];
  float edv = ed3[i];
  float denom = 0.f;
  float2 acc = make_float2(0.f, 0.f);
  int e8end = base + ((end - base) & ~7);
  for (int e = base; e < e8end; e += 8) {
    int e0 = e + 2 * g;
    int s0 = elist[e0], s1 = elist[e0 + 1];
    float f0 = es3[s0], f1 = es3[s1];
    __half2 r0 = hb2[(size_t)s0 * 16 + cl];
    __half2 r1 = hb2[(size_t)s1 * 16 + cl];
    float x0 = __expf(lrelu(f0 + edv));
    float x1 = __expf(lrelu(f1 + edv));
    denom += x0 + x1;
    float2 h0 = __half22float2(r0), h1 = __half22float2(r1);
    acc.x = fmaf(x0, h0.x, fmaf(x1, h1.x, acc.x));
    acc.y = fmaf(x0, h0.y, fmaf(x1, h1.y, acc.y));
  }
  for (int e = e8end + g; e < end; e += 4) {
    int s0 = elist[e];
    float x0 = __expf(lrelu(es3[s0] + edv));
    __half2 r0 = hb2[(size_t)s0 * 16 + cl];
    denom += x0;
    float2 h0 = __half22float2(r0);
    acc.x = fmaf(x0, h0.x, acc.x);
    acc.y = fmaf(x0, h0.y, acc.y);
  }
#pragma unroll
  for (int off = 16; off < 64; off <<= 1) {
    denom += __shfl_xor(denom, off);
    acc.x += __shfl_xor(acc.x, off);
    acc.y += __shfl_xor(acc.y, off);
  }
  if (g == 0) {
    float inv = 1.f / (denom + 1e-16f);
    float2 o;
    o.x = fmaf(acc.x, inv, b3[2 * cl]);
    o.y = fmaf(acc.y, inv, b3[2 * cl + 1]);
    ((float2*)(emb + (size_t)i * OUTD))[cl] = o;
  }
}

// ---------------- MLP head (c1 computed per-block) ----------------
__global__ __launch_bounds__(256) void mlp_k(
    const float* __restrict__ emb, const int* __restrict__ srcn,
    const float* __restrict__ Wm1, const float* __restrict__ bm1,
    const float* __restrict__ Wm2, const float* __restrict__ bm2,
    const float* __restrict__ Wm3, const float* __restrict__ bm3,
    float* __restrict__ outp) {
  __shared__ float WL1s[32][64];
  __shared__ float WL2s[64][32];
  __shared__ float W3s[32];
  __shared__ float c1s[64];
  __shared__ float zsrc[32];
  int t = threadIdx.x;
  int sn = srcn[0];
  if (t < 32) zsrc[t] = emb[(size_t)sn * OUTD + t];
  for (int q = t; q < 2048; q += 256) WL1s[q >> 6][q & 63] = Wm1[(32 + (q >> 6)) * 64 + (q & 63)];
  for (int q = t; q < 2048; q += 256) WL2s[q >> 5][q & 31] = Wm2[q];
  if (t < 32) W3s[t] = Wm3[t];
  __syncthreads();
  if (t < 64) {
    float a = bm1[t];
#pragma unroll 8
    for (int k = 0; k < 32; ++k) a = fmaf(zsrc[k], Wm1[k * 64 + t], a);
    c1s[t] = a;
  }
  __syncthreads();
  int wv = t >> 6, lane = t & 63;
  int p = lane >> 5, c = lane & 31;
  float bm2v = bm2[c];
  float bm3v = bm3[0];
  for (int node = blockIdx.x * 4 + wv; node < NN; node += gridDim.x * 4) {
    float zv = (lane < 32) ? emb[(size_t)node * OUTD + lane] : 0.f;
    float a1 = c1s[lane];
#pragma unroll
    for (int k = 0; k < 32; ++k) a1 = fmaf(__shfl(zv, k), WL1s[k][lane], a1);
    float u1 = fmaxf(a1, 0.f);
    float a2 = 0.f;
#pragma unroll
    for (int j = 0; j < 32; ++j) a2 = fmaf(__shfl(u1, p * 32 + j), WL2s[p * 32 + j][c], a2);
    a2 += __shfl_xor(a2, 32);
    float v = 0.f;
    if (lane < 32) {
      float u2 = fmaxf(a2 + bm2v, 0.f);
      v = u2 * W3s[c];
    }
    v = wred_sum(v);
    if (lane == 0) outp[node] = 1.f / (1.f + __expf(-(v + bm3v)));
  }
}

// ---------------- host launcher ----------------
extern "C" void kernel_launch(void* const* d_in, const int* in_sizes, int n_in,
                              void* d_out, int out_size, void* d_ws, size_t ws_size,
                              hipStream_t stream) {
  const float* x   = (const float*)d_in[0];
  const int* eidx  = (const int*)d_in[1];
  const int* srcn  = (const int*)d_in[2];
  const float* W1  = (const float*)d_in[3];
  const float* as1 = (const float*)d_in[4];
  const float* ad1 = (const float*)d_in[5];
  const float* b1  = (const float*)d_in[6];
  const float* g1  = (const float*)d_in[7];
  const float* be1 = (const float*)d_in[8];
  const float* W2  = (const float*)d_in[9];
  const float* as2 = (const float*)d_in[10];
  const float* ad2 = (const float*)d_in[11];
  const float* b2  = (const float*)d_in[12];
  const float* g2  = (const float*)d_in[13];
  const float* be2 = (const float*)d_in[14];
  const float* W3  = (const float*)d_in[15];
  const float* as3 = (const float*)d_in[16];
  const float* ad3 = (const float*)d_in[17];
  const float* b3  = (const float*)d_in[18];
  const float* Wm1 = (const float*)d_in[19];
  const float* bm1 = (const float*)d_in[20];
  const float* Wm2 = (const float*)d_in[21];
  const float* bm2 = (const float*)d_in[22];
  const float* Wm3 = (const float*)d_in[23];
  const float* bm3 = (const float*)d_in[24];
  float* outp = (float*)d_out;

  // workspace carve (256B-aligned chunks)
  char* wp = (char*)d_ws;
  auto carve = [&](size_t bytes) {
    void* p = (void*)wp;
    wp += (bytes + 255) & ~(size_t)255;
    return p;
  };
  __half* aggB  = (__half*)carve((size_t)NN * HC * 2);   // fp16 agg output
  __half* hbuf  = (__half*)carve((size_t)NN * HC * 2);   // fp16 h
  __half* h3h   = (__half*)carve((size_t)NN * OUTD * 2); // fp16 h3
  float* emb    = (float*)carve((size_t)NN * OUTD * 4);
  float* es     = (float*)carve((size_t)NN * HEADS * 4);
  float* ed     = (float*)carve((size_t)NN * HEADS * 4);
  float* es3    = (float*)carve((size_t)NN * 4);
  float* ed3    = (float*)carve((size_t)NN * 4);
  float* bnsums = (float*)carve(2 * HC * 4);
  __half* Bh    = (__half*)carve((size_t)HC * HC * 2);   // swizzled W2 fp16
  __half* Bh3   = (__half*)carve((size_t)HC * OUTD * 2); // swizzled W3 fp16
  int* offs     = (int*)carve((NN + 4) * 4);
  int* cursor   = (int*)carve(NN * 4);
  int* elist    = (int*)carve((size_t)ETOT * 4);
  int* part     = (int*)carve(NN * 4);
  int* bsum     = (int*)carve(256 * 4);

  const int TB = 256;
  const int gE = (ETOT + TB - 1) / TB;
  const int gN4 = (NN + 3) / 4;            // 12500

  // ---- CSR build ----
  hipMemsetAsync(cursor, 0, (size_t)NN * 4, stream);
  hist_k<<<gE, TB, 0, stream>>>(eidx, cursor);
  scan1_k<<<NB1, TB, 0, stream>>>(cursor, part, bsum);
  scan23_k<<<NB1, TB, 0, stream>>>(part, bsum, offs, cursor);
  scatter_k<<<gE, TB, 0, stream>>>(eidx, cursor, elist);
  wswz_both_k<<<(HC * HC + HC * OUTD + TB - 1) / TB, TB, 0, stream>>>(W2, W3, Bh, Bh3);

  // ---- layer 1 ----
  l1_h_k<<<2048, TB, 0, stream>>>(x, W1, as1, ad1, hbuf, es, ed);
  gat_agg256<<<gN4, TB, 0, stream>>>(hbuf, es, ed, offs, elist, b1, aggB, bnsums);
  bn_stats_k<<<(NN + 63) / 64, TB, 0, stream>>>(aggB, bnsums);

  // ---- layer 2: MFMA GEMM (BN1 affine computed in-kernel; es2/ed2 fused) ----
  gemm_mfma_k<<<dim3((NN + 127) / 128, HC / 128), TB, 0, stream>>>(
      aggB, Bh, bnsums, g1, be1, as2, ad2, hbuf, es, ed);
  gat_agg256<<<gN4, TB, 0, stream>>>(hbuf, es, ed, offs, elist, b2, aggB, bnsums);
  bn_stats_k<<<(NN + 63) / 64, TB, 0, stream>>>(aggB, bnsums);

  // ---- layer 3: MFMA (BN2 affine computed in-kernel; es3/ed3 fused) ----
  l3_mfma_k<<<(NN + 127) / 128, TB, 0, stream>>>(
      aggB, Bh3, bnsums, g2, be2, as3, ad3, h3h, es3, ed3);
  gat_agg32<<<gN4, TB, 0, stream>>>(h3h, es3, ed3, offs, elist, b3, emb);

  // ---- MLP head ----
  mlp_k<<<512, TB, 0, stream>>>(emb, srcn, Wm1, bm1, Wm2, bm2, Wm3, bm3, outp);
}